// Round 16
// baseline (78.088 us; speedup 1.0000x reference)
//
#include <hip/hip_runtime.h>
#include <math.h>

#define L      2048
#define DDIM   512
#define NBATCH 8
#define BM     256
#define BN     128
#define BK     64
#define NKT    (DDIM / BK)               // 8 K-tiles
#define NKTI   (L / BN)                  // 16 col-tiles
#define PAIRS  72                        // sum_{tj=0..7} (16 - 2*tj)
#define TOTAL_BLOCKS (NBATCH * PAIRS)    // 576

#define ALPHA  0.1f
#define BETA   0.3f
#define MARGIN 2.0f

typedef _Float16 f16x8 __attribute__((ext_vector_type(8)));
typedef __attribute__((ext_vector_type(4))) float f32x4;

// LDS ring-2: buffer = A[256 rows x 64 f16] (32 KB) + B[128 rows x 64 f16]
// (16 KB) = 48 KB; x2 = 96 KB dynamic. Rows 128B = 8 chunks of 16B;
// physical chunk = logical ^ (row & 7)  (R8/R12-proven conflict-free).
#define TILE_A  16384      // f16
#define BUFSZ   24576      // f16 per buffer
#define LDS_BYTES (2 * BUFSZ * 2)   // 98304

#define GLOAD_LDS16(g, l) __builtin_amdgcn_global_load_lds(              \
    (const __attribute__((address_space(1))) unsigned int*)(g),          \
    (__attribute__((address_space(3))) unsigned int*)(l), 16, 0, 0)

// ---------------------------------------------------------------------------
// Kernel 1: fp32 -> fp16 + per-row squared norms (exact fp32).
// ---------------------------------------------------------------------------
__global__ __launch_bounds__(256) void conv_kernel(const float* __restrict__ pred,
                                                   _Float16* __restrict__ h,
                                                   float* __restrict__ sq) {
    int w    = threadIdx.x >> 6;
    int lane = threadIdx.x & 63;
    int row  = blockIdx.x * 4 + w;
    const float* p = pred + (size_t)row * DDIM + lane * 8;
    float4 v0 = *(const float4*)(p);
    float4 v1 = *(const float4*)(p + 4);
    float vals[8] = {v0.x, v0.y, v0.z, v0.w, v1.x, v1.y, v1.z, v1.w};
    f16x8 hv;
    float s = 0.0f;
    #pragma unroll
    for (int i = 0; i < 8; ++i) {
        float x = vals[i];
        s = fmaf(x, x, s);
        hv[i] = (_Float16)x;
    }
    *(f16x8*)(h + (size_t)row * DDIM + lane * 8) = hv;
    #pragma unroll
    for (int off = 32; off > 0; off >>= 1) s += __shfl_down(s, off);
    if (lane == 0) sq[row] = s;
}

// ---------------------------------------------------------------------------
// Kernel 2: fp16 Gram GEMM, R13 phase-split schedule + symmetry.
// 256x128 tile, 8 waves (4M x 2N, per-wave 64x64 = 4x4 frags of 16x16x32),
// BK=64, ring-2 96KB LDS (1 block/CU, 8 waves), 4 phases per K-tile over
// output quadrants (2x2 frags each):
//  ph0: vmcnt(0); bar; read a01+b01; STAGE(j+1); lgkm0; 8 MFMA Q(0,0)
//  ph1: bar; read b23; lgkm0; 8 MFMA Q(0,1)
//  ph2: bar; read a23; lgkm0; 8 MFMA Q(1,1)
//  ph3: bar; 8 MFMA Q(1,0) (no reads)
// Symmetric grid (tk >= 2*tj), per-element weights {2,1,0}.
// ---------------------------------------------------------------------------
__global__ __launch_bounds__(512) void loss_kernel(
        const _Float16* __restrict__ h,
        const int*   __restrict__ seg,
        const float* __restrict__ sq,
        double*      __restrict__ partials) {
    extern __shared__ _Float16 smem[];
    __shared__ double wred[8];

    int bid = blockIdx.x;
    int n = bid & 7;            // batch -> XCD round-robin (L2 locality)
    int p = bid >> 3;           // 0..71
    int tj = 0;                 // widths 16,14,...,2
    while (p >= NKTI - 2 * tj) { p -= NKTI - 2 * tj; ++tj; }
    int tk = 2 * tj + p;
    int j0 = tj * BM, k0 = tk * BN;

    int t    = threadIdx.x;
    int wid  = t >> 6;          // 0..7
    int lane = t & 63;
    int wm   = wid >> 1;        // 0..3 : 64-row band of 256
    int wn   = wid & 1;         // 0..1 : 64-col band of 128
    int l15  = lane & 15;
    int lq   = lane >> 4;       // 0..3 : k-quarter

    const _Float16* baseH = h + (size_t)n * L * DDIM;

    // staging: inst = 8 rows x 128B (1KB). lane -> row rl8 = lane>>3,
    // logical chunk lc = (lane&7) ^ rl8 (source pre-swizzle; row&7 == rl8).
    // Wave: A insts {4w..4w+3} (rows (4w+q)*8..), B insts {2w..2w+1}.
    int rl8 = lane >> 3;
    int lc  = (lane & 7) ^ rl8;
    const _Float16* srcA = baseH + (size_t)(j0 + wid * 32 + rl8) * DDIM + lc * 8;
    const _Float16* srcB = baseH + (size_t)(k0 + wid * 16 + rl8) * DDIM + lc * 8;

    #define STAGE(j)                                                          \
    {                                                                         \
        _Float16* _A = smem + ((j) & 1) * BUFSZ + wid * 2048;                 \
        _Float16* _B = smem + ((j) & 1) * BUFSZ + TILE_A + wid * 1024;        \
        _Pragma("unroll")                                                     \
        for (int q = 0; q < 4; ++q)                                           \
            GLOAD_LDS16(srcA + (size_t)(q * 8) * DDIM + (j) * BK,             \
                        _A + q * 512);                                        \
        _Pragma("unroll")                                                     \
        for (int q = 0; q < 2; ++q)                                           \
            GLOAD_LDS16(srcB + (size_t)(q * 8) * DDIM + (j) * BK,             \
                        _B + q * 512);                                        \
    }

    // LDS frag read helpers: row R (f16 row stride 64), chunk kc = k2*4+lq,
    // physical chunk = kc ^ (R & 7); R & 7 == l15 & 7.
    int s7 = l15 & 7;
    int arow[4], brow[4];
    #pragma unroll
    for (int f = 0; f < 4; ++f) {
        arow[f] = (wm * 64 + f * 16 + l15) * 64;
        brow[f] = TILE_A + (wn * 64 + f * 16 + l15) * 64;
    }
    int xk[2] = { ((0 + lq) ^ s7) << 3, ((4 + lq) ^ s7) << 3 };

    f32x4 acc[4][4];
    #pragma unroll
    for (int mf = 0; mf < 4; ++mf)
        #pragma unroll
        for (int nf = 0; nf < 4; ++nf) acc[mf][nf] = (f32x4){0.f, 0.f, 0.f, 0.f};

    STAGE(0);   // prologue

    #pragma unroll 2
    for (int j = 0; j < NKT; ++j) {
        const _Float16* B0 = smem + (j & 1) * BUFSZ;

        // ---------------- ph0: Q(0,0) ----------------
        asm volatile("s_waitcnt vmcnt(0)" ::: "memory");   // tile-j loads done
        __builtin_amdgcn_s_barrier();
        f16x8 a01[2][2], b01[2][2];
        #pragma unroll
        for (int f = 0; f < 2; ++f)
            #pragma unroll
            for (int k2 = 0; k2 < 2; ++k2) {
                a01[f][k2] = *(const f16x8*)&B0[arow[f] + xk[k2]];
                b01[f][k2] = *(const f16x8*)&B0[brow[f] + xk[k2]];
            }
        if (j + 1 < NKT) STAGE(j + 1);                     // into other buffer
        asm volatile("s_waitcnt lgkmcnt(0)" ::: "memory");
        __builtin_amdgcn_sched_barrier(0);
        __builtin_amdgcn_s_setprio(1);
        #pragma unroll
        for (int mf = 0; mf < 2; ++mf)
            #pragma unroll
            for (int nf = 0; nf < 2; ++nf)
                #pragma unroll
                for (int k2 = 0; k2 < 2; ++k2)
                    acc[mf][nf] = __builtin_amdgcn_mfma_f32_16x16x32_f16(
                        a01[mf][k2], b01[nf][k2], acc[mf][nf], 0, 0, 0);
        __builtin_amdgcn_s_setprio(0);

        // ---------------- ph1: Q(0,1) ----------------
        __builtin_amdgcn_s_barrier();
        f16x8 b23[2][2];
        #pragma unroll
        for (int f = 0; f < 2; ++f)
            #pragma unroll
            for (int k2 = 0; k2 < 2; ++k2)
                b23[f][k2] = *(const f16x8*)&B0[brow[f + 2] + xk[k2]];
        asm volatile("s_waitcnt lgkmcnt(0)" ::: "memory");
        __builtin_amdgcn_sched_barrier(0);
        __builtin_amdgcn_s_setprio(1);
        #pragma unroll
        for (int mf = 0; mf < 2; ++mf)
            #pragma unroll
            for (int nf = 0; nf < 2; ++nf)
                #pragma unroll
                for (int k2 = 0; k2 < 2; ++k2)
                    acc[mf][nf + 2] = __builtin_amdgcn_mfma_f32_16x16x32_f16(
                        a01[mf][k2], b23[nf][k2], acc[mf][nf + 2], 0, 0, 0);
        __builtin_amdgcn_s_setprio(0);

        // ---------------- ph2: Q(1,1) ----------------
        __builtin_amdgcn_s_barrier();
        f16x8 a23[2][2];
        #pragma unroll
        for (int f = 0; f < 2; ++f)
            #pragma unroll
            for (int k2 = 0; k2 < 2; ++k2)
                a23[f][k2] = *(const f16x8*)&B0[arow[f + 2] + xk[k2]];
        asm volatile("s_waitcnt lgkmcnt(0)" ::: "memory");
        __builtin_amdgcn_sched_barrier(0);
        __builtin_amdgcn_s_setprio(1);
        #pragma unroll
        for (int mf = 0; mf < 2; ++mf)
            #pragma unroll
            for (int nf = 0; nf < 2; ++nf)
                #pragma unroll
                for (int k2 = 0; k2 < 2; ++k2)
                    acc[mf + 2][nf + 2] = __builtin_amdgcn_mfma_f32_16x16x32_f16(
                        a23[mf][k2], b23[nf][k2], acc[mf + 2][nf + 2], 0, 0, 0);
        __builtin_amdgcn_s_setprio(0);

        // ---------------- ph3: Q(1,0) (no reads) ----------------
        __builtin_amdgcn_s_barrier();
        __builtin_amdgcn_s_setprio(1);
        #pragma unroll
        for (int mf = 0; mf < 2; ++mf)
            #pragma unroll
            for (int nf = 0; nf < 2; ++nf)
                #pragma unroll
                for (int k2 = 0; k2 < 2; ++k2)
                    acc[mf + 2][nf] = __builtin_amdgcn_mfma_f32_16x16x32_f16(
                        a23[mf][k2], b01[nf][k2], acc[mf + 2][nf], 0, 0, 0);
        __builtin_amdgcn_s_setprio(0);
    }

    // ------------------- fused loss epilogue -------------------
    // 16x16 C/D layout: col = lane&15, row = lq*4 + reg
    const int*   segb = seg + n * L;
    const float* sqb  = sq + n * L;

    float lsum = 0.0f;    // weighted: skip j>k, 2x for j<k, 1x for j==k
    #pragma unroll
    for (int nf = 0; nf < 4; ++nf) {
        int k = k0 + wn * 64 + nf * 16 + l15;
        float sqk = sqb[k];
        int   sgk = segb[k];
        #pragma unroll
        for (int mf = 0; mf < 4; ++mf)
            #pragma unroll
            for (int reg = 0; reg < 4; ++reg) {
                int jj = j0 + wm * 64 + mf * 16 + lq * 4 + reg;
                if (jj > k) continue;
                float inner = acc[mf][nf][reg];
                float d2 = fmaxf(sqb[jj] + sqk - 2.0f * inner, 0.0f);
                float v;
                if (segb[jj] == sgk) {
                    v = ALPHA * d2;
                } else {
                    float dist = sqrtf(d2);
                    float hg = fmaxf(MARGIN - dist, 0.0f);
                    v = BETA * hg * hg;
                }
                lsum += (jj < k) ? 2.0f * v : v;
            }
    }

    double dsum = (double)lsum;
    #pragma unroll
    for (int off = 32; off > 0; off >>= 1)
        dsum += __shfl_down(dsum, off);
    if (lane == 0) wred[wid] = dsum;
    __syncthreads();
    if (t == 0) {
        double s = ((wred[0] + wred[1]) + (wred[2] + wred[3]))
                 + ((wred[4] + wred[5]) + (wred[6] + wred[7]));
        partials[bid] = s;
    }
}

// ---------------------------------------------------------------------------
// Kernel 3: deterministic final reduction -> mean.
// ---------------------------------------------------------------------------
__global__ __launch_bounds__(256) void reduce_kernel(const double* __restrict__ partials,
                                                     float* __restrict__ out,
                                                     int nPart, double invCount) {
    __shared__ double red[256];
    int t = threadIdx.x;
    double s = 0.0;
    for (int i = t; i < nPart; i += 256) s += partials[i];
    red[t] = s;
    __syncthreads();
    #pragma unroll
    for (int k = 128; k > 0; k >>= 1) {
        if (t < k) red[t] += red[t + k];
        __syncthreads();
    }
    if (t == 0) out[0] = (float)(red[0] * invCount);
}

extern "C" void kernel_launch(void* const* d_in, const int* in_sizes, int n_in,
                              void* d_out, int out_size, void* d_ws, size_t ws_size,
                              hipStream_t stream) {
    const float* pred = (const float*)d_in[0];
    const int*   seg  = (const int*)d_in[1];
    float* out = (float*)d_out;

    const size_t HALF = (size_t)NBATCH * L * DDIM;
    _Float16* h        = (_Float16*)d_ws;                    // 16.78 MB
    float*    sq       = (float*)(h + HALF);                 // 64 KB
    double*   partials = (double*)(sq + NBATCH * L);         // 4.6 KB

    // allow 96KB dynamic LDS (idempotent; safe under graph capture, R10/R13)
    (void)hipFuncSetAttribute((const void*)loss_kernel,
                              hipFuncAttributeMaxDynamicSharedMemorySize,
                              LDS_BYTES);

    conv_kernel<<<NBATCH * L / 4, 256, 0, stream>>>(pred, h, sq);
    loss_kernel<<<TOTAL_BLOCKS, 512, LDS_BYTES, stream>>>(h, seg, sq, partials);
    reduce_kernel<<<1, 256, 0, stream>>>(partials, out, TOTAL_BLOCKS,
                                         1.0 / (double)((size_t)NBATCH * L * L));
}

// Round 17
// 62.592 us; speedup vs baseline: 1.2476x; 1.2476x over previous
//
#include <hip/hip_runtime.h>
#include <math.h>

#define L      2048
#define DDIM   512
#define NBATCH 8
#define BM     128
#define BN     128
#define BK     64
#define NKT    (DDIM / BK)               // 8 K-tiles
#define NTILE  (L / BM)                  // 16
#define NPAIR  (NTILE * (NTILE + 1) / 2) // 136
#define TOTAL_BLOCKS (NBATCH * NPAIR)    // 1088

#define ALPHA  0.1f
#define BETA   0.3f
#define MARGIN 2.0f

typedef _Float16 f16x8 __attribute__((ext_vector_type(8)));
typedef __attribute__((ext_vector_type(16))) float f32x16;

#define TILE_SH 8192       // f16 per tile (16 KB)
#define BUFSZ   16384      // f16 per buffer (32 KB)

#define GLOAD_LDS16(g, l) __builtin_amdgcn_global_load_lds(              \
    (const __attribute__((address_space(1))) unsigned int*)(g),          \
    (__attribute__((address_space(3))) unsigned int*)(l), 16, 0, 0)

// ---------------------------------------------------------------------------
// Kernel 1: fp32 -> fp16 + per-row squared norms. XCD-ALIGNED with consumer:
// block b -> batch = b & 7 (same placement key as loss_kernel), so batch n's
// h lands dirty-resident in XCD n's L2 (2.1 MB < 4 MiB).
// ---------------------------------------------------------------------------
__global__ __launch_bounds__(256) void conv_kernel(const float* __restrict__ pred,
                                                   _Float16* __restrict__ h,
                                                   float* __restrict__ sq) {
    int w     = threadIdx.x >> 6;
    int lane  = threadIdx.x & 63;
    int batch = blockIdx.x & 7;                 // -> XCD (round-robin)
    int idx   = blockIdx.x >> 3;                // 0..511
    int row   = batch * L + idx * 4 + w;
    const float* p = pred + (size_t)row * DDIM + lane * 8;
    float4 v0 = *(const float4*)(p);
    float4 v1 = *(const float4*)(p + 4);
    float vals[8] = {v0.x, v0.y, v0.z, v0.w, v1.x, v1.y, v1.z, v1.w};
    f16x8 hv;
    float s = 0.0f;
    #pragma unroll
    for (int i = 0; i < 8; ++i) {
        float x = vals[i];
        s = fmaf(x, x, s);
        hv[i] = (_Float16)x;
    }
    *(f16x8*)(h + (size_t)row * DDIM + lane * 8) = hv;
    #pragma unroll
    for (int off = 32; off > 0; off >>= 1) s += __shfl_down(s, off);
    if (lane == 0) sq[row] = s;
}

// ---------------------------------------------------------------------------
// Kernel 2: fp16 Gram GEMM + fused loss (R15 structure, setprio removed).
// 128x128, 4 waves, mfma_f32_32x32x16_f16, BK=64, dbuf 64KB (2 blocks/CU),
// zero-VALU K-loop (full unroll, persistent pointers + immediates),
// STAGE(kt+1) first, 16 ds_read, 16 MFMA, vmcnt(0), ONE s_barrier per tile.
// ---------------------------------------------------------------------------
__global__ __launch_bounds__(256) void loss_kernel(
        const _Float16* __restrict__ h,
        const int*   __restrict__ seg,
        const float* __restrict__ sq,
        double*      __restrict__ partials) {
    __shared__ _Float16 smem[2 * BUFSZ];   // 64 KB
    __shared__ double wred[4];

    int bid = blockIdx.x;
    int n = bid & 7;            // batch -> XCD (matches conv placement)
    int p = bid >> 3;           // 0..135
    int tj = 0;
    while (true) {
        int rl2 = NTILE - tj;
        if (p < rl2) break;
        p -= rl2;
        ++tj;
    }
    int tk = tj + p;
    int j0 = tj * BM, k0 = tk * BN;

    int t    = threadIdx.x;
    int w    = t >> 6;          // 0..3
    int lane = t & 63;
    int wr   = w >> 1, wc = w & 1;     // 64x64 quadrant
    int l31  = lane & 31;
    int hsel = lane >> 5;              // 0/1: k-halfslice of the frag

    const _Float16* baseH = h + (size_t)n * L * DDIM;

    int rl8 = lane >> 3;
    int lc  = (lane & 7) ^ rl8;
    const _Float16* srcA = baseH + (size_t)(j0 + w * 32 + rl8) * DDIM + lc * 8;
    const _Float16* srcB = baseH + (size_t)(k0 + w * 32 + rl8) * DDIM + lc * 8;
    _Float16* dstA = smem + w * 2048;            // A inst base (f16 units)
    _Float16* dstB = smem + TILE_SH + w * 2048;  // B inst base

    #define STAGE(kt, cur)                                                    \
    {                                                                         \
        _Pragma("unroll")                                                     \
        for (int q = 0; q < 4; ++q) {                                         \
            GLOAD_LDS16(srcA + (size_t)(q * 8) * DDIM + (kt) * BK,            \
                        dstA + (cur) * BUFSZ + q * 512);                      \
            GLOAD_LDS16(srcB + (size_t)(q * 8) * DDIM + (kt) * BK,            \
                        dstB + (cur) * BUFSZ + q * 512);                      \
        }                                                                     \
    }

    // persistent per-lane LDS read indices (f16 units), loop-invariant
    int s7 = l31 & 7;
    int ra = (wr * 64 + l31) * 64;
    int rb = (wc * 64 + l31) * 64 + TILE_SH;
    int iA0 = ra + (((0 + hsel) ^ s7) << 3);
    int iA1 = ra + (((2 + hsel) ^ s7) << 3);
    int iA2 = ra + (((4 + hsel) ^ s7) << 3);
    int iA3 = ra + (((6 + hsel) ^ s7) << 3);
    int iB0 = rb + (((0 + hsel) ^ s7) << 3);
    int iB1 = rb + (((2 + hsel) ^ s7) << 3);
    int iB2 = rb + (((4 + hsel) ^ s7) << 3);
    int iB3 = rb + (((6 + hsel) ^ s7) << 3);

    f32x16 acc[2][2];
    #pragma unroll
    for (int m = 0; m < 2; ++m)
        #pragma unroll
        for (int nn = 0; nn < 2; ++nn)
            #pragma unroll
            for (int r = 0; r < 16; ++r) acc[m][nn][r] = 0.0f;

    STAGE(0, 0);
    asm volatile("s_waitcnt vmcnt(0)" ::: "memory");
    __builtin_amdgcn_s_barrier();

    #pragma unroll
    for (int kt = 0; kt < NKT; ++kt) {
        const int cur = kt & 1;                  // compile-time under unroll
        if (kt + 1 < NKT) STAGE(kt + 1, cur ^ 1);

        #pragma unroll
        for (int ks = 0; ks < 4; ++ks) {
            int iA = (ks == 0) ? iA0 : (ks == 1) ? iA1 : (ks == 2) ? iA2 : iA3;
            int iB = (ks == 0) ? iB0 : (ks == 1) ? iB1 : (ks == 2) ? iB2 : iB3;
            f16x8 a0 = *(const f16x8*)&smem[iA + cur * BUFSZ];
            f16x8 a1 = *(const f16x8*)&smem[iA + cur * BUFSZ + 2048];
            f16x8 b0 = *(const f16x8*)&smem[iB + cur * BUFSZ];
            f16x8 b1 = *(const f16x8*)&smem[iB + cur * BUFSZ + 2048];
            acc[0][0] = __builtin_amdgcn_mfma_f32_32x32x16_f16(a0, b0, acc[0][0], 0, 0, 0);
            acc[0][1] = __builtin_amdgcn_mfma_f32_32x32x16_f16(a0, b1, acc[0][1], 0, 0, 0);
            acc[1][0] = __builtin_amdgcn_mfma_f32_32x32x16_f16(a1, b0, acc[1][0], 0, 0, 0);
            acc[1][1] = __builtin_amdgcn_mfma_f32_32x32x16_f16(a1, b1, acc[1][1], 0, 0, 0);
        }

        asm volatile("s_waitcnt vmcnt(0)" ::: "memory");
        __builtin_amdgcn_s_barrier();
    }

    // ------------------- fused loss epilogue -------------------
    // 32x32 C/D layout: col = lane&31, row = (reg&3) + 8*(reg>>2) + 4*(lane>>5)
    const int*   segb = seg + n * L;
    const float* sqb  = sq + n * L;

    float lsum = 0.0f;
    #pragma unroll
    for (int nn = 0; nn < 2; ++nn) {
        int k = k0 + wc * 64 + nn * 32 + l31;
        float sqk = sqb[k];
        int   sgk = segb[k];
        #pragma unroll
        for (int m = 0; m < 2; ++m)
            #pragma unroll
            for (int r = 0; r < 16; ++r) {
                int j = j0 + wr * 64 + m * 32 + (r & 3) + 8 * (r >> 2) + 4 * hsel;
                float inner = acc[m][nn][r];
                float d2 = fmaxf(sqb[j] + sqk - 2.0f * inner, 0.0f);
                float v;
                if (segb[j] == sgk) {
                    v = ALPHA * d2;
                } else {
                    float dist = sqrtf(d2);
                    float hg = fmaxf(MARGIN - dist, 0.0f);
                    v = BETA * hg * hg;
                }
                lsum += v;
            }
    }

    double wgt = (tj == tk) ? 1.0 : 2.0;
    double dsum = (double)lsum * wgt;
    #pragma unroll
    for (int off = 32; off > 0; off >>= 1)
        dsum += __shfl_down(dsum, off);
    if (lane == 0) wred[w] = dsum;
    __syncthreads();
    if (t == 0) partials[bid] = (wred[0] + wred[1]) + (wred[2] + wred[3]);
}

// ---------------------------------------------------------------------------
// Kernel 3: deterministic final reduction -> mean.
// ---------------------------------------------------------------------------
__global__ __launch_bounds__(256) void reduce_kernel(const double* __restrict__ partials,
                                                     float* __restrict__ out,
                                                     int nPart, double invCount) {
    __shared__ double red[256];
    int t = threadIdx.x;
    double s = 0.0;
    for (int i = t; i < nPart; i += 256) s += partials[i];
    red[t] = s;
    __syncthreads();
    #pragma unroll
    for (int k = 128; k > 0; k >>= 1) {
        if (t < k) red[t] += red[t + k];
        __syncthreads();
    }
    if (t == 0) out[0] = (float)(red[0] * invCount);
}

extern "C" void kernel_launch(void* const* d_in, const int* in_sizes, int n_in,
                              void* d_out, int out_size, void* d_ws, size_t ws_size,
                              hipStream_t stream) {
    const float* pred = (const float*)d_in[0];
    const int*   seg  = (const int*)d_in[1];
    float* out = (float*)d_out;

    const size_t HALF = (size_t)NBATCH * L * DDIM;
    _Float16* h        = (_Float16*)d_ws;                    // 16.78 MB
    float*    sq       = (float*)(h + HALF);                 // 64 KB
    double*   partials = (double*)(sq + NBATCH * L);         // 8.7 KB

    conv_kernel<<<NBATCH * L / 4, 256, 0, stream>>>(pred, h, sq);
    loss_kernel<<<TOTAL_BLOCKS, 256, 0, stream>>>(h, seg, sq, partials);
    reduce_kernel<<<1, 256, 0, stream>>>(partials, out, TOTAL_BLOCKS,
                                         1.0 / (double)((size_t)NBATCH * L * L));
}

// Round 18
// 61.486 us; speedup vs baseline: 1.2700x; 1.0180x over previous
//
#include <hip/hip_runtime.h>
#include <math.h>

#define L      2048
#define DDIM   512
#define NBATCH 8
#define BM     128
#define BN     128
#define BK     128                       // super-tile: 2 k-halves of 64
#define NST    (DDIM / BK)               // 4 super-tiles
#define NTILE  (L / BM)                  // 16
#define NPAIR  (NTILE * (NTILE + 1) / 2) // 136
#define TOTAL_BLOCKS (NBATCH * NPAIR)    // 1088

#define ALPHA  0.1f
#define BETA   0.3f
#define MARGIN 2.0f

typedef _Float16 f16x8 __attribute__((ext_vector_type(8)));
typedef __attribute__((ext_vector_type(16))) float f32x16;

// Single 64KB buffer: A = [kh(2)][128 rows][64 f16] at 0, B same at +16384.
// Rows 128B = 8 chunks of 16B; physical chunk = logical ^ (row & 7)
// (R8/R12/R17-proven conflict-free).
#define AHALF  8192        // f16 per k-half tile (16 KB)
#define BOFF   16384       // f16 offset of B

#define GLOAD_LDS16(g, l) __builtin_amdgcn_global_load_lds(              \
    (const __attribute__((address_space(1))) unsigned int*)(g),          \
    (__attribute__((address_space(3))) unsigned int*)(l), 16, 0, 0)

// ---------------------------------------------------------------------------
// Kernel 1: fp32 -> fp16 + per-row squared norms. XCD-aligned with consumer.
// ---------------------------------------------------------------------------
__global__ __launch_bounds__(256) void conv_kernel(const float* __restrict__ pred,
                                                   _Float16* __restrict__ h,
                                                   float* __restrict__ sq) {
    int w     = threadIdx.x >> 6;
    int lane  = threadIdx.x & 63;
    int batch = blockIdx.x & 7;
    int idx   = blockIdx.x >> 3;
    int row   = batch * L + idx * 4 + w;
    const float* p = pred + (size_t)row * DDIM + lane * 8;
    float4 v0 = *(const float4*)(p);
    float4 v1 = *(const float4*)(p + 4);
    float vals[8] = {v0.x, v0.y, v0.z, v0.w, v1.x, v1.y, v1.z, v1.w};
    f16x8 hv;
    float s = 0.0f;
    #pragma unroll
    for (int i = 0; i < 8; ++i) {
        float x = vals[i];
        s = fmaf(x, x, s);
        hv[i] = (_Float16)x;
    }
    *(f16x8*)(h + (size_t)row * DDIM + lane * 8) = hv;
    #pragma unroll
    for (int off = 32; off > 0; off >>= 1) s += __shfl_down(s, off);
    if (lane == 0) sq[row] = s;
}

// ---------------------------------------------------------------------------
// Kernel 2: fp16 Gram GEMM + fused loss. A/B test vs R17: SAME staged bytes,
// HALF the phases. BK=128, single 64KB buffer, 4 phases of
// {sync; STAGE(16 gload); sync; 32 ds_read + 32 MFMA per wave}.
// 128x128, 4 waves, mfma_f32_32x32x16_f16, 2 blocks/CU, zero-VALU K-loop.
// ---------------------------------------------------------------------------
__global__ __launch_bounds__(256) void loss_kernel(
        const _Float16* __restrict__ h,
        const int*   __restrict__ seg,
        const float* __restrict__ sq,
        double*      __restrict__ partials) {
    __shared__ _Float16 smem[32768];   // 64 KB
    __shared__ double wred[4];

    int bid = blockIdx.x;
    int n = bid & 7;            // batch -> XCD
    int p = bid >> 3;           // 0..135
    int tj = 0;
    while (true) {
        int rl2 = NTILE - tj;
        if (p < rl2) break;
        p -= rl2;
        ++tj;
    }
    int tk = tj + p;
    int j0 = tj * BM, k0 = tk * BN;

    int t    = threadIdx.x;
    int w    = t >> 6;          // 0..3
    int lane = t & 63;
    int wr   = w >> 1, wc = w & 1;     // 64x64 quadrant
    int l31  = lane & 31;
    int hsel = lane >> 5;              // 0/1: k-halfslice of the frag

    const _Float16* baseH = h + (size_t)n * L * DDIM;

    // staging: inst = 8 rows x 128B (1KB); lane -> row rl8 = lane>>3,
    // logical chunk lc = (lane&7) ^ rl8 (source pre-swizzle; row&7 == rl8).
    // Wave w covers rows w*32..w*32+31 of A and of B, for both k-halves.
    int rl8 = lane >> 3;
    int lc  = (lane & 7) ^ rl8;
    const _Float16* srcA = baseH + (size_t)(j0 + w * 32 + rl8) * DDIM + lc * 8;
    const _Float16* srcB = baseH + (size_t)(k0 + w * 32 + rl8) * DDIM + lc * 8;
    _Float16* dstA = smem + w * 2048;          // + kh*AHALF + q*512
    _Float16* dstB = smem + BOFF + w * 2048;

    // 16 gload_lds per thread per super-tile (4 q x 2 kh x {A,B})
    #define STAGE(st)                                                         \
    {                                                                         \
        _Pragma("unroll")                                                     \
        for (int q = 0; q < 4; ++q)                                           \
            _Pragma("unroll")                                                 \
            for (int kh = 0; kh < 2; ++kh) {                                  \
                GLOAD_LDS16(srcA + (size_t)(q * 8) * DDIM + (st) * BK + kh * 64, \
                            dstA + kh * AHALF + q * 512);                     \
                GLOAD_LDS16(srcB + (size_t)(q * 8) * DDIM + (st) * BK + kh * 64, \
                            dstB + kh * AHALF + q * 512);                     \
            }                                                                 \
    }

    // persistent per-lane LDS read indices (f16 units), loop-invariant;
    // chunk c = (ks&3)*2 + hsel, physical = c ^ (row&7); kh adds AHALF.
    int s7 = l31 & 7;
    int ra = (wr * 64 + l31) * 64;
    int rb = (wc * 64 + l31) * 64 + BOFF;
    int iA0 = ra + (((0 + hsel) ^ s7) << 3);
    int iA1 = ra + (((2 + hsel) ^ s7) << 3);
    int iA2 = ra + (((4 + hsel) ^ s7) << 3);
    int iA3 = ra + (((6 + hsel) ^ s7) << 3);
    int iB0 = rb + (((0 + hsel) ^ s7) << 3);
    int iB1 = rb + (((2 + hsel) ^ s7) << 3);
    int iB2 = rb + (((4 + hsel) ^ s7) << 3);
    int iB3 = rb + (((6 + hsel) ^ s7) << 3);

    f32x16 acc[2][2];
    #pragma unroll
    for (int m = 0; m < 2; ++m)
        #pragma unroll
        for (int nn = 0; nn < 2; ++nn)
            #pragma unroll
            for (int r = 0; r < 16; ++r) acc[m][nn][r] = 0.0f;

    #pragma unroll
    for (int st = 0; st < NST; ++st) {
        __syncthreads();               // previous phase done reading LDS
        STAGE(st);
        __syncthreads();               // compiler drains vmcnt before barrier

        #pragma unroll
        for (int ks = 0; ks < 8; ++ks) {
            int kq = ks & 3;
            int kh = ks >> 2;
            int iA = ((kq == 0) ? iA0 : (kq == 1) ? iA1 : (kq == 2) ? iA2 : iA3)
                     + kh * AHALF;
            int iB = ((kq == 0) ? iB0 : (kq == 1) ? iB1 : (kq == 2) ? iB2 : iB3)
                     + kh * AHALF;
            f16x8 a0 = *(const f16x8*)&smem[iA];
            f16x8 a1 = *(const f16x8*)&smem[iA + 2048];
            f16x8 b0 = *(const f16x8*)&smem[iB];
            f16x8 b1 = *(const f16x8*)&smem[iB + 2048];
            acc[0][0] = __builtin_amdgcn_mfma_f32_32x32x16_f16(a0, b0, acc[0][0], 0, 0, 0);
            acc[0][1] = __builtin_amdgcn_mfma_f32_32x32x16_f16(a0, b1, acc[0][1], 0, 0, 0);
            acc[1][0] = __builtin_amdgcn_mfma_f32_32x32x16_f16(a1, b0, acc[1][0], 0, 0, 0);
            acc[1][1] = __builtin_amdgcn_mfma_f32_32x32x16_f16(a1, b1, acc[1][1], 0, 0, 0);
        }
    }

    // ------------------- fused loss epilogue -------------------
    // 32x32 C/D layout: col = lane&31, row = (reg&3) + 8*(reg>>2) + 4*(lane>>5)
    const int*   segb = seg + n * L;
    const float* sqb  = sq + n * L;

    float lsum = 0.0f;
    #pragma unroll
    for (int nn = 0; nn < 2; ++nn) {
        int k = k0 + wc * 64 + nn * 32 + l31;
        float sqk = sqb[k];
        int   sgk = segb[k];
        #pragma unroll
        for (int m = 0; m < 2; ++m)
            #pragma unroll
            for (int r = 0; r < 16; ++r) {
                int j = j0 + wr * 64 + m * 32 + (r & 3) + 8 * (r >> 2) + 4 * hsel;
                float inner = acc[m][nn][r];
                float d2 = fmaxf(sqb[j] + sqk - 2.0f * inner, 0.0f);
                float v;
                if (segb[j] == sgk) {
                    v = ALPHA * d2;
                } else {
                    float dist = sqrtf(d2);
                    float hg = fmaxf(MARGIN - dist, 0.0f);
                    v = BETA * hg * hg;
                }
                lsum += v;
            }
    }

    double wgt = (tj == tk) ? 1.0 : 2.0;
    double dsum = (double)lsum * wgt;
    #pragma unroll
    for (int off = 32; off > 0; off >>= 1)
        dsum += __shfl_down(dsum, off);
    if (lane == 0) wred[w] = dsum;
    __syncthreads();
    if (t == 0) partials[bid] = (wred[0] + wred[1]) + (wred[2] + wred[3]);
}

// ---------------------------------------------------------------------------
// Kernel 3: deterministic final reduction -> mean.
// ---------------------------------------------------------------------------
__global__ __launch_bounds__(256) void reduce_kernel(const double* __restrict__ partials,
                                                     float* __restrict__ out,
                                                     int nPart, double invCount) {
    __shared__ double red[256];
    int t = threadIdx.x;
    double s = 0.0;
    for (int i = t; i < nPart; i += 256) s += partials[i];
    red[t] = s;
    __syncthreads();
    #pragma unroll
    for (int k = 128; k > 0; k >>= 1) {
        if (t < k) red[t] += red[t + k];
        __syncthreads();
    }
    if (t == 0) out[0] = (float)(red[0] * invCount);
}

extern "C" void kernel_launch(void* const* d_in, const int* in_sizes, int n_in,
                              void* d_out, int out_size, void* d_ws, size_t ws_size,
                              hipStream_t stream) {
    const float* pred = (const float*)d_in[0];
    const int*   seg  = (const int*)d_in[1];
    float* out = (float*)d_out;

    const size_t HALF = (size_t)NBATCH * L * DDIM;
    _Float16* h        = (_Float16*)d_ws;                    // 16.78 MB
    float*    sq       = (float*)(h + HALF);                 // 64 KB
    double*   partials = (double*)(sq + NBATCH * L);         // 8.7 KB

    conv_kernel<<<NBATCH * L / 4, 256, 0, stream>>>(pred, h, sq);
    loss_kernel<<<TOTAL_BLOCKS, 256, 0, stream>>>(h, seg, sq, partials);
    reduce_kernel<<<1, 256, 0, stream>>>(partials, out, TOTAL_BLOCKS,
                                         1.0 / (double)((size_t)NBATCH * L * L));
}

// Round 19
// 55.844 us; speedup vs baseline: 1.3983x; 1.1010x over previous
//
#include <hip/hip_runtime.h>
#include <hip/hip_fp8.h>
#include <math.h>

#define L      2048
#define DDIM   512
#define NBATCH 8
#define BM     128
#define BN     128
#define BK     128                       // elements per super-tile row (128 B)
#define NST    (DDIM / BK)               // 4 super-tiles
#define NTILE  (L / BM)                  // 16
#define NPAIR  (NTILE * (NTILE + 1) / 2) // 136
#define TOTAL_BLOCKS (NBATCH * NPAIR)    // 1088

#define ALPHA  0.1f
#define BETA   0.3f
#define MARGIN 2.0f

typedef __attribute__((ext_vector_type(16))) float f32x16;
typedef _Float16 f16x8 __attribute__((ext_vector_type(8)));   // (unused size ref)

// LDS single buffer 32 KB: A[128 rows x 128 B] at 0, B same at +16384.
// Row = 8 chunks of 16 B; physical chunk = logical ^ (row & 7)
// (R8/R12/R17/R18-proven conflict-free; b64 reads are 2-way worst = free).
#define BOFF   16384       // bytes, offset of B tile

#define GLOAD_LDS16(g, l) __builtin_amdgcn_global_load_lds(              \
    (const __attribute__((address_space(1))) unsigned int*)(g),          \
    (__attribute__((address_space(3))) unsigned int*)(l), 16, 0, 0)

// ---------------------------------------------------------------------------
// Kernel 1: fp32 -> fp8 e4m3 (RNE via HIP type) + EXACT fp32 sq norms.
// XCD-aligned with consumer (block b -> batch b&7).
// ---------------------------------------------------------------------------
__global__ __launch_bounds__(256) void conv_kernel(const float* __restrict__ pred,
                                                   unsigned char* __restrict__ h,
                                                   float* __restrict__ sq) {
    int w     = threadIdx.x >> 6;
    int lane  = threadIdx.x & 63;
    int batch = blockIdx.x & 7;
    int idx   = blockIdx.x >> 3;
    int row   = batch * L + idx * 4 + w;
    const float* p = pred + (size_t)row * DDIM + lane * 8;
    float4 v0 = *(const float4*)(p);
    float4 v1 = *(const float4*)(p + 4);
    float vals[8] = {v0.x, v0.y, v0.z, v0.w, v1.x, v1.y, v1.z, v1.w};
    unsigned q[8];
    float s = 0.0f;
    #pragma unroll
    for (int i = 0; i < 8; ++i) {
        float x = vals[i];
        s = fmaf(x, x, s);
        __hip_fp8_e4m3 f8(x);              // OCP e4m3, RNE (gfx950 native)
        q[i] = (unsigned)f8.__x;
    }
    unsigned lo = q[0] | (q[1] << 8) | (q[2] << 16) | (q[3] << 24);
    unsigned hi = q[4] | (q[5] << 8) | (q[6] << 16) | (q[7] << 24);
    *(uint2*)(h + (size_t)row * DDIM + lane * 8) = make_uint2(lo, hi);
    #pragma unroll
    for (int off = 32; off > 0; off >>= 1) s += __shfl_down(s, off);
    if (lane == 0) sq[row] = s;
}

// ---------------------------------------------------------------------------
// Kernel 2: fp8 Gram GEMM + fused loss. R18 structure, HALF the staged bytes.
// 128x128 tile, 4 waves, mfma_f32_32x32x16_fp8_fp8 (bf16 rate), BK=128 elems.
// 4 phases of {sync; STAGE (8 gload_lds); sync; 8 ks x (4 ds_read_b64 pairs
// + 4 MFMA)}. Single 32 KB buffer. sq exact-fp32 + quantized inner =>
// unbiased off-diagonal d2 (error ~5e-5 absolute on the mean).
// ---------------------------------------------------------------------------
__global__ __launch_bounds__(256) void loss_kernel(
        const unsigned char* __restrict__ h,
        const int*   __restrict__ seg,
        const float* __restrict__ sq,
        double*      __restrict__ partials) {
    __shared__ unsigned char smem[32768];   // 32 KB
    __shared__ double wred[4];

    int bid = blockIdx.x;
    int n = bid & 7;            // batch -> XCD
    int p = bid >> 3;           // 0..135
    int tj = 0;
    while (true) {
        int rl2 = NTILE - tj;
        if (p < rl2) break;
        p -= rl2;
        ++tj;
    }
    int tk = tj + p;
    int j0 = tj * BM, k0 = tk * BN;

    int t    = threadIdx.x;
    int w    = t >> 6;          // 0..3
    int lane = t & 63;
    int wr   = w >> 1, wc = w & 1;     // 64x64 quadrant
    int l31  = lane & 31;
    int hsel = lane >> 5;              // 0/1: byte-half of the 16B k-chunk

    const unsigned char* baseH = h + (size_t)n * L * DDIM;

    // staging: inst = 8 rows x 128 B (1 KB); lane -> row rl8 = lane>>3,
    // logical 16B-chunk lc = (lane&7) ^ rl8 (pre-swizzled source).
    int rl8 = lane >> 3;
    int lc  = (lane & 7) ^ rl8;
    const unsigned char* srcA = baseH + (size_t)(j0 + w * 32 + rl8) * DDIM + lc * 16;
    const unsigned char* srcB = baseH + (size_t)(k0 + w * 32 + rl8) * DDIM + lc * 16;
    unsigned char* dstA = smem + w * 4096;          // 4 insts x 1 KB per wave
    unsigned char* dstB = smem + BOFF + w * 4096;

    #define STAGE(st)                                                         \
    {                                                                         \
        _Pragma("unroll")                                                     \
        for (int q = 0; q < 4; ++q) {                                         \
            GLOAD_LDS16(srcA + (size_t)(q * 8) * DDIM + (st) * BK,            \
                        dstA + q * 1024);                                     \
            GLOAD_LDS16(srcB + (size_t)(q * 8) * DDIM + (st) * BK,            \
                        dstB + q * 1024);                                     \
        }                                                                     \
    }

    // frag read bases (bytes): row R stride 128 B; chunk ks ^ (R&7);
    // R & 7 == l31 & 7 for all frags (row offsets are multiples of 32).
    int s7  = l31 & 7;
    int rab = (wr * 64 + l31) * 128 + hsel * 8;          // A, m=0 (+4096 m=1)
    int rbb = BOFF + (wc * 64 + l31) * 128 + hsel * 8;   // B, nn=0 (+4096 nn=1)

    f32x16 acc[2][2];
    #pragma unroll
    for (int m = 0; m < 2; ++m)
        #pragma unroll
        for (int nn = 0; nn < 2; ++nn)
            #pragma unroll
            for (int r = 0; r < 16; ++r) acc[m][nn][r] = 0.0f;

    #pragma unroll
    for (int st = 0; st < NST; ++st) {
        __syncthreads();               // previous phase done reading LDS
        STAGE(st);
        __syncthreads();               // compiler drains vmcnt before barrier

        #pragma unroll
        for (int ks = 0; ks < 8; ++ks) {
            int xo = (ks ^ s7) << 4;
            long a0 = *(const long*)&smem[rab + xo];
            long a1 = *(const long*)&smem[rab + 4096 + xo];
            long b0 = *(const long*)&smem[rbb + xo];
            long b1 = *(const long*)&smem[rbb + 4096 + xo];
            acc[0][0] = __builtin_amdgcn_mfma_f32_32x32x16_fp8_fp8(a0, b0, acc[0][0], 0, 0, 0);
            acc[0][1] = __builtin_amdgcn_mfma_f32_32x32x16_fp8_fp8(a0, b1, acc[0][1], 0, 0, 0);
            acc[1][0] = __builtin_amdgcn_mfma_f32_32x32x16_fp8_fp8(a1, b0, acc[1][0], 0, 0, 0);
            acc[1][1] = __builtin_amdgcn_mfma_f32_32x32x16_fp8_fp8(a1, b1, acc[1][1], 0, 0, 0);
        }
    }

    // ------------------- fused loss epilogue -------------------
    // 32x32 C/D layout: col = lane&31, row = (reg&3) + 8*(reg>>2) + 4*(lane>>5)
    const int*   segb = seg + n * L;
    const float* sqb  = sq + n * L;

    float lsum = 0.0f;
    #pragma unroll
    for (int nn = 0; nn < 2; ++nn) {
        int k = k0 + wc * 64 + nn * 32 + l31;
        float sqk = sqb[k];
        int   sgk = segb[k];
        #pragma unroll
        for (int m = 0; m < 2; ++m)
            #pragma unroll
            for (int r = 0; r < 16; ++r) {
                int j = j0 + wr * 64 + m * 32 + (r & 3) + 8 * (r >> 2) + 4 * hsel;
                float inner = acc[m][nn][r];
                float d2 = fmaxf(sqb[j] + sqk - 2.0f * inner, 0.0f);
                float v;
                if (segb[j] == sgk) {
                    v = ALPHA * d2;
                } else {
                    float dist = sqrtf(d2);
                    float hg = fmaxf(MARGIN - dist, 0.0f);
                    v = BETA * hg * hg;
                }
                lsum += v;
            }
    }

    double wgt = (tj == tk) ? 1.0 : 2.0;
    double dsum = (double)lsum * wgt;
    #pragma unroll
    for (int off = 32; off > 0; off >>= 1)
        dsum += __shfl_down(dsum, off);
    if (lane == 0) wred[w] = dsum;
    __syncthreads();
    if (t == 0) partials[bid] = (wred[0] + wred[1]) + (wred[2] + wred[3]);
}

// ---------------------------------------------------------------------------
// Kernel 3: deterministic final reduction -> mean.
// ---------------------------------------------------------------------------
__global__ __launch_bounds__(256) void reduce_kernel(const double* __restrict__ partials,
                                                     float* __restrict__ out,
                                                     int nPart, double invCount) {
    __shared__ double red[256];
    int t = threadIdx.x;
    double s = 0.0;
    for (int i = t; i < nPart; i += 256) s += partials[i];
    red[t] = s;
    __syncthreads();
    #pragma unroll
    for (int k = 128; k > 0; k >>= 1) {
        if (t < k) red[t] += red[t + k];
        __syncthreads();
    }
    if (t == 0) out[0] = (float)(red[0] * invCount);
}

extern "C" void kernel_launch(void* const* d_in, const int* in_sizes, int n_in,
                              void* d_out, int out_size, void* d_ws, size_t ws_size,
                              hipStream_t stream) {
    const float* pred = (const float*)d_in[0];
    const int*   seg  = (const int*)d_in[1];
    float* out = (float*)d_out;

    const size_t HALF = (size_t)NBATCH * L * DDIM;
    unsigned char* h  = (unsigned char*)d_ws;                // 8.39 MB fp8
    float*  sq        = (float*)(h + HALF);                  // 64 KB
    double* partials  = (double*)(sq + NBATCH * L);          // 8.7 KB

    conv_kernel<<<NBATCH * L / 4, 256, 0, stream>>>(pred, h, sq);
    loss_kernel<<<TOTAL_BLOCKS, 256, 0, stream>>>(h, seg, sq, partials);
    reduce_kernel<<<1, 256, 0, stream>>>(partials, out, TOTAL_BLOCKS,
                                         1.0 / (double)((size_t)NBATCH * L * L));
}